// Round 3
// baseline (749.138 us; speedup 1.0000x reference)
//
#include <hip/hip_runtime.h>

#define TT 64
#define CC 384
#define NH 6
#define HID 1536
#define LDX 392   // attn kernel: padded cols (2-way-free bank layout)
#define LDH 72    // attn head tiles

typedef __bf16 bf16x8 __attribute__((ext_vector_type(8)));
typedef float f32x4 __attribute__((ext_vector_type(4)));
typedef unsigned short us8 __attribute__((ext_vector_type(8)));

#define MFMA(a, b, c) __builtin_amdgcn_mfma_f32_16x16x32_bf16(a, b, c, 0, 0, 0)

static __device__ __forceinline__ unsigned short f2bf(float f) {
  unsigned u = __builtin_bit_cast(unsigned, f);
  u += 0x7FFFu + ((u >> 16) & 1u);
  return (unsigned short)(u >> 16);
}
static __device__ __forceinline__ float bf2f(unsigned short h) {
  unsigned u = ((unsigned)h) << 16;
  return __builtin_bit_cast(float, u);
}
static __device__ __forceinline__ bf16x8 ld8(const unsigned short* p) {
  return __builtin_bit_cast(bf16x8, *reinterpret_cast<const us8*>(p));
}

// ---- weight prep: fp32 -> bf16, transposed to [n][k] for MFMA B-frags ----
__global__ void prep_w(const float* __restrict__ Wq, const float* __restrict__ Wk,
                       const float* __restrict__ Wv, const float* __restrict__ Wo,
                       const float* __restrict__ W1, const float* __restrict__ W2,
                       unsigned short* __restrict__ ws) {
  const int T0 = 1152 * 384;            // Wqkv [h*192+j][k]
  const int T1 = T0 + 384 * 384;        // WoT  [n][k]
  const int T2 = T1 + 1536 * 384;       // W1T  [n][k]
  const int T3 = T2 + 384 * 1536;       // W2T  [n][k]
  for (int i = blockIdx.x * blockDim.x + threadIdx.x; i < T3; i += gridDim.x * blockDim.x) {
    float v;
    if (i < T0) {
      int n = i / 384, k = i % 384;
      int hh = n / 192, j = n % 192;
      const float* W = (j < 64) ? Wq : (j < 128) ? Wk : Wv;
      int d = (j < 64) ? j : (j < 128) ? j - 64 : j - 128;
      v = W[((size_t)hh * 384 + k) * 64 + d];
    } else if (i < T1) {
      int i2 = i - T0; int n = i2 / 384, k = i2 % 384;
      v = Wo[(size_t)k * 384 + n];
    } else if (i < T2) {
      int i2 = i - T1; int n = i2 / 384, k = i2 % 384;
      v = W1[(size_t)k * 1536 + n];
    } else {
      int i2 = i - T2; int n = i2 / 1536, k = i2 % 1536;
      v = W2[(size_t)k * 384 + n];
    }
    ws[i] = f2bf(v);
  }
}

// ---- kernel A: LN1 + attention + per-head proj accumulation + residual -> x2 (=d_out, fp32)
__global__ __launch_bounds__(256, 2)
void attn_fwd(const float* __restrict__ x,
              const float* __restrict__ ln1g, const float* __restrict__ ln1b,
              const float* __restrict__ bo,
              const unsigned short* __restrict__ Wqkv,
              const unsigned short* __restrict__ WoT,
              float* __restrict__ x2) {
  __shared__ unsigned short sXN[TT * LDX];       // xn1 (bf16)
  __shared__ unsigned short sHEAD[3 * TT * LDH]; // q | k (later att_h) | vT
  unsigned short* sQ = sHEAD;                    // q [t][d]; later P [t][s]
  unsigned short* sK = sHEAD + TT * LDH;         // k [s][d]; later att_h [t][d]
  unsigned short* sV = sHEAD + 2 * TT * LDH;     // vT [d][s]

  const int b = blockIdx.x;
  const int tid = threadIdx.x;
  const int wv = tid >> 6;
  const int ln = tid & 63;
  const int l16 = ln & 15;
  const int lg = ln >> 4;
  const float* xb = x + (size_t)b * TT * CC;
  const f32x4 Z4 = {0.f, 0.f, 0.f, 0.f};

  // ---------- LN1 ----------
  for (int r = wv * 16; r < wv * 16 + 16; ++r) {
    float v[6], s = 0.f, sq = 0.f;
#pragma unroll
    for (int j = 0; j < 6; ++j) { v[j] = xb[r * CC + ln + 64 * j]; s += v[j]; sq += v[j] * v[j]; }
#pragma unroll
    for (int off = 32; off; off >>= 1) { s += __shfl_xor(s, off); sq += __shfl_xor(sq, off); }
    float mu = s * (1.f / CC);
    float rs = rsqrtf(sq * (1.f / CC) - mu * mu + 1e-5f);
#pragma unroll
    for (int j = 0; j < 6; ++j) {
      int c = ln + 64 * j;
      sXN[r * LDX + c] = f2bf((v[j] - mu) * rs * ln1g[c] + ln1b[c]);
    }
  }
  __syncthreads();

  // persistent proj accumulator (rows m*16+lg*4+rg, cols wv*96+c*16+l16)
  f32x4 pacc[4][6];
#pragma unroll
  for (int m = 0; m < 4; ++m)
#pragma unroll
    for (int c = 0; c < 6; ++c) pacc[m][c] = Z4;

  for (int h = 0; h < NH; ++h) {
    // ----- qkv = xn @ Wh : 64 x 192, wave stripe cols [48*wv, 48*wv+48)
    const unsigned short* Wh = Wqkv + (size_t)(h * 192) * CC;
    f32x4 qacc[4][3];
#pragma unroll
    for (int m = 0; m < 4; ++m)
#pragma unroll
      for (int c = 0; c < 3; ++c) qacc[m][c] = Z4;
    for (int kk = 0; kk < CC; kk += 32) {
      bf16x8 a[4];
#pragma unroll
      for (int m = 0; m < 4; ++m)
        a[m] = ld8(&sXN[(m * 16 + l16) * LDX + kk + 8 * lg]);
      __builtin_amdgcn_s_setprio(1);
#pragma unroll
      for (int c = 0; c < 3; ++c) {
        int n = wv * 48 + c * 16 + l16;
        bf16x8 bb = ld8(&Wh[(size_t)n * CC + kk + 8 * lg]);
#pragma unroll
        for (int m = 0; m < 4; ++m) qacc[m][c] = MFMA(a[m], bb, qacc[m][c]);
      }
      __builtin_amdgcn_s_setprio(0);
    }
    __syncthreads();  // B1: prior head's proj reads of sK / PV reads of sV done
    // scatter: q [t][d], k [s][d], vT [d][s]
#pragma unroll
    for (int m = 0; m < 4; ++m)
#pragma unroll
      for (int c = 0; c < 3; ++c) {
        int n = wv * 48 + c * 16 + l16;
#pragma unroll
        for (int rg = 0; rg < 4; ++rg) {
          int t = m * 16 + lg * 4 + rg;
          unsigned short bv = f2bf(qacc[m][c][rg]);
          if (n < 64) sQ[t * LDH + n] = bv;
          else if (n < 128) sK[t * LDH + (n - 64)] = bv;
          else sV[(n - 128) * LDH + t] = bv;
        }
      }
    __syncthreads();  // B2

    // ----- S = q.kT for this wave's 16 rows
    f32x4 sacc[4];
#pragma unroll
    for (int c = 0; c < 4; ++c) sacc[c] = Z4;
#pragma unroll
    for (int kk = 0; kk < 64; kk += 32) {
      bf16x8 a = ld8(&sQ[(wv * 16 + l16) * LDH + kk + 8 * lg]);
#pragma unroll
      for (int c = 0; c < 4; ++c) {
        bf16x8 bb = ld8(&sK[(c * 16 + l16) * LDH + kk + 8 * lg]);
        sacc[c] = MFMA(a, bb, sacc[c]);
      }
    }
    // causal softmax (rows in 16-lane groups), P overlays q (own rows)
#pragma unroll
    for (int rg = 0; rg < 4; ++rg) {
      int row = wv * 16 + lg * 4 + rg;
      float e[4], mx = -1e30f;
#pragma unroll
      for (int c = 0; c < 4; ++c) {
        int col = c * 16 + l16;
        float vv = sacc[c][rg] * 0.125f;
        e[c] = (col <= row) ? vv : -1e30f;
        mx = fmaxf(mx, e[c]);
      }
#pragma unroll
      for (int off = 8; off; off >>= 1) mx = fmaxf(mx, __shfl_xor(mx, off));
      float sum = 0.f;
#pragma unroll
      for (int c = 0; c < 4; ++c) {
        int col = c * 16 + l16;
        e[c] = (col <= row) ? __expf(e[c] - mx) : 0.f;
        sum += e[c];
      }
#pragma unroll
      for (int off = 8; off; off >>= 1) sum += __shfl_xor(sum, off);
      float inv = 1.f / sum;
#pragma unroll
      for (int c = 0; c < 4; ++c)
        sQ[row * LDH + c * 16 + l16] = f2bf(e[c] * inv);
    }
    // ----- out_h = P @ V (own 16 rows); same-wave LDS ops are ordered
    f32x4 oacc[4];
#pragma unroll
    for (int c = 0; c < 4; ++c) oacc[c] = Z4;
#pragma unroll
    for (int kk = 0; kk < 64; kk += 32) {
      bf16x8 a = ld8(&sQ[(wv * 16 + l16) * LDH + kk + 8 * lg]);
#pragma unroll
      for (int c = 0; c < 4; ++c) {
        bf16x8 bb = ld8(&sV[(c * 16 + l16) * LDH + kk + 8 * lg]);
        oacc[c] = MFMA(a, bb, oacc[c]);
      }
    }
    __syncthreads();  // B3: all waves done reading sK (S phase)
    // stage att_h into sK region [t][d]
#pragma unroll
    for (int c = 0; c < 4; ++c)
#pragma unroll
      for (int rg = 0; rg < 4; ++rg) {
        int t = wv * 16 + lg * 4 + rg;
        sK[t * LDH + c * 16 + l16] = f2bf(oacc[c][rg]);
      }
    __syncthreads();  // B4: att_h visible

    // ----- proj accumulate: pacc += att_h @ WoT[:, h*64 .. h*64+63]
    __builtin_amdgcn_s_setprio(1);
#pragma unroll
    for (int kk = 0; kk < 64; kk += 32) {
      bf16x8 a[4];
#pragma unroll
      for (int m = 0; m < 4; ++m)
        a[m] = ld8(&sK[(m * 16 + l16) * LDH + kk + 8 * lg]);
#pragma unroll
      for (int c = 0; c < 6; ++c) {
        int n = wv * 96 + c * 16 + l16;
        bf16x8 bb = ld8(&WoT[(size_t)n * CC + h * 64 + kk + 8 * lg]);
#pragma unroll
        for (int m = 0; m < 4; ++m) pacc[m][c] = MFMA(a[m], bb, pacc[m][c]);
      }
    }
    __builtin_amdgcn_s_setprio(0);
  }

  // ---------- x2 = x + proj + bo (fp32, to d_out) ----------
  float* xo = x2 + (size_t)b * TT * CC;
#pragma unroll
  for (int m = 0; m < 4; ++m)
#pragma unroll
    for (int c = 0; c < 6; ++c) {
      int n = wv * 96 + c * 16 + l16;
      float bov = bo[n];
#pragma unroll
      for (int rg = 0; rg < 4; ++rg) {
        int t = m * 16 + lg * 4 + rg;
        xo[t * CC + n] = xb[t * CC + n] + pacc[m][c][rg] + bov;
      }
    }
}

// ---- kernel B: LN2 + MLP + residual; 512 thr / 8 waves; XOR-swizzled LDS (80KB exactly)
// x2 lives in d_out, overwritten in place.
__global__ __launch_bounds__(512, 4)
void mlp_fwd(const float* __restrict__ ln2g, const float* __restrict__ ln2b,
             const float* __restrict__ b1, const float* __restrict__ b2,
             const unsigned short* __restrict__ W1T,
             const unsigned short* __restrict__ W2T,
             float* xo) {
  __shared__ unsigned short sXN[TT * 384];  // xn2 (bf16), XOR-swizzled, 48KB
  __shared__ unsigned short sH[TT * 256];   // relu(h) chunk (bf16), XOR-swizzled, 32KB

  const int b = blockIdx.x;
  const int tid = threadIdx.x;
  const int wv = tid >> 6;      // 0..7
  const int ln = tid & 63;
  const int l16 = ln & 15;
  const int lg = ln >> 4;
  const int sw = (l16 & 7) << 3;  // A-frag read swizzle (row = *+l16)
  float* xb = xo + (size_t)b * TT * CC;  // x2 rows (read-then-overwrite)
  const f32x4 Z4 = {0.f, 0.f, 0.f, 0.f};

  // ---------- LN2: 8 waves x 8 rows ----------
  for (int r = wv * 8; r < wv * 8 + 8; ++r) {
    float v[6], s = 0.f, sq = 0.f;
#pragma unroll
    for (int j = 0; j < 6; ++j) { v[j] = xb[r * CC + ln + 64 * j]; s += v[j]; sq += v[j] * v[j]; }
#pragma unroll
    for (int off = 32; off; off >>= 1) { s += __shfl_xor(s, off); sq += __shfl_xor(sq, off); }
    float mu = s * (1.f / CC);
    float rs = rsqrtf(sq * (1.f / CC) - mu * mu + 1e-5f);
#pragma unroll
    for (int j = 0; j < 6; ++j) {
      int c = ln + 64 * j;
      sXN[r * 384 + (c ^ ((r & 7) << 3))] = f2bf((v[j] - mu) * rs * ln2g[c] + ln2b[c]);
    }
  }
  __syncthreads();

  // ---------- MLP: 6 chunks of 256 hidden cols ----------
  // GEMM1: wave owns 32 cols (2 c-tiles) x all 64 rows; GEMM2: wave owns 48 cols x all rows.
  f32x4 macc[4][3];
#pragma unroll
  for (int m = 0; m < 4; ++m)
#pragma unroll
    for (int c = 0; c < 3; ++c) macc[m][c] = Z4;

  for (int ch = 0; ch < 6; ++ch) {
    f32x4 hacc[4][2];
#pragma unroll
    for (int m = 0; m < 4; ++m)
#pragma unroll
      for (int c = 0; c < 2; ++c) hacc[m][c] = Z4;
    for (int kk = 0; kk < CC; kk += 32) {
      bf16x8 a[4];
#pragma unroll
      for (int m = 0; m < 4; ++m)
        a[m] = ld8(&sXN[(m * 16 + l16) * 384 + ((kk + 8 * lg) ^ sw)]);
      __builtin_amdgcn_s_setprio(1);
#pragma unroll
      for (int c = 0; c < 2; ++c) {
        int ng = ch * 256 + wv * 32 + c * 16 + l16;
        bf16x8 bb = ld8(&W1T[(size_t)ng * CC + kk + 8 * lg]);
#pragma unroll
        for (int m = 0; m < 4; ++m) hacc[m][c] = MFMA(a[m], bb, hacc[m][c]);
      }
      __builtin_amdgcn_s_setprio(0);
    }
    __syncthreads();  // prior GEMM2 reads of sH done
#pragma unroll
    for (int m = 0; m < 4; ++m)
#pragma unroll
      for (int c = 0; c < 2; ++c) {
        int nl = wv * 32 + c * 16 + l16;
        float b1v = b1[ch * 256 + nl];
#pragma unroll
        for (int rg = 0; rg < 4; ++rg) {
          int t = m * 16 + lg * 4 + rg;
          sH[t * 256 + (nl ^ ((t & 7) << 3))] = f2bf(fmaxf(hacc[m][c][rg] + b1v, 0.f));
        }
      }
    __syncthreads();  // h chunk visible
    for (int kk = 0; kk < 256; kk += 32) {
      bf16x8 a[4];
#pragma unroll
      for (int m = 0; m < 4; ++m)
        a[m] = ld8(&sH[(m * 16 + l16) * 256 + ((kk + 8 * lg) ^ sw)]);
      __builtin_amdgcn_s_setprio(1);
#pragma unroll
      for (int c = 0; c < 3; ++c) {
        int n = wv * 48 + c * 16 + l16;
        bf16x8 bb = ld8(&W2T[(size_t)n * HID + ch * 256 + kk + 8 * lg]);
#pragma unroll
        for (int m = 0; m < 4; ++m) macc[m][c] = MFMA(a[m], bb, macc[m][c]);
      }
      __builtin_amdgcn_s_setprio(0);
    }
  }
  // ---------- out = x2 + mlp + b2 (read-before-write, same buffer) ----------
#pragma unroll
  for (int m = 0; m < 4; ++m)
#pragma unroll
    for (int c = 0; c < 3; ++c) {
      int n = wv * 48 + c * 16 + l16;
      float b2v = b2[n];
#pragma unroll
      for (int rg = 0; rg < 4; ++rg) {
        int t = m * 16 + lg * 4 + rg;
        size_t idx = (size_t)t * CC + n;
        float x2v = xb[idx];
        xb[idx] = x2v + macc[m][c][rg] + b2v;
      }
    }
}

extern "C" void kernel_launch(void* const* d_in, const int* in_sizes, int n_in,
                              void* d_out, int out_size, void* d_ws, size_t ws_size,
                              hipStream_t stream) {
  const float* x    = (const float*)d_in[0];
  const float* ln1g = (const float*)d_in[1];
  const float* ln1b = (const float*)d_in[2];
  const float* Wq   = (const float*)d_in[3];
  const float* Wk   = (const float*)d_in[4];
  const float* Wv   = (const float*)d_in[5];
  const float* Wo   = (const float*)d_in[6];
  const float* bo   = (const float*)d_in[7];
  const float* ln2g = (const float*)d_in[8];
  const float* ln2b = (const float*)d_in[9];
  const float* W1   = (const float*)d_in[10];
  const float* b1   = (const float*)d_in[11];
  const float* W2   = (const float*)d_in[12];
  const float* b2   = (const float*)d_in[13];
  unsigned short* ws = (unsigned short*)d_ws;

  const size_t need = (size_t)(1152 * 384 + 384 * 384 + 1536 * 384 + 384 * 1536) * 2;
  if (ws_size < need) return;

  hipLaunchKernelGGL(prep_w, dim3(1024), dim3(256), 0, stream, Wq, Wk, Wv, Wo, W1, W2, ws);

  const unsigned short* Wqkv = ws;
  const unsigned short* WoT  = ws + 1152 * 384;
  const unsigned short* W1T  = WoT + 384 * 384;
  const unsigned short* W2T  = W1T + 1536 * 384;
  int nblk = in_sizes[0] / (TT * CC);

  hipLaunchKernelGGL(attn_fwd, dim3(nblk), dim3(256), 0, stream,
                     x, ln1g, ln1b, bo, Wqkv, WoT, (float*)d_out);
  hipLaunchKernelGGL(mlp_fwd, dim3(nblk), dim3(512), 0, stream,
                     ln2g, ln2b, b1, b2, W1T, W2T, (float*)d_out);
}

// Round 4
// 512.502 us; speedup vs baseline: 1.4617x; 1.4617x over previous
//
#include <hip/hip_runtime.h>

#define TT 64
#define CC 384
#define NH 6
#define HID 1536
#define LDX 392   // padded cols for 64x384 bf16 tiles
#define LDH 72    // head tiles (144B stride)
#define LDM 200   // mlp h-chunk (192+8)

typedef __bf16 bf16x8 __attribute__((ext_vector_type(8)));
typedef float f32x4 __attribute__((ext_vector_type(4)));
typedef unsigned short us8 __attribute__((ext_vector_type(8)));

#define MFMA(a, b, c) __builtin_amdgcn_mfma_f32_16x16x32_bf16(a, b, c, 0, 0, 0)

static __device__ __forceinline__ unsigned short f2bf(float f) {
  unsigned u = __builtin_bit_cast(unsigned, f);
  u += 0x7FFFu + ((u >> 16) & 1u);
  return (unsigned short)(u >> 16);
}
static __device__ __forceinline__ float bf2f(unsigned short h) {
  unsigned u = ((unsigned)h) << 16;
  return __builtin_bit_cast(float, u);
}
static __device__ __forceinline__ bf16x8 ld8(const unsigned short* p) {
  return __builtin_bit_cast(bf16x8, *reinterpret_cast<const us8*>(p));
}

// ---- weight prep: fp32 -> bf16, transposed to [n][k] for MFMA B-frags ----
__global__ void prep_w(const float* __restrict__ Wq, const float* __restrict__ Wk,
                       const float* __restrict__ Wv, const float* __restrict__ Wo,
                       const float* __restrict__ W1, const float* __restrict__ W2,
                       unsigned short* __restrict__ ws) {
  const int T0 = 1152 * 384;            // Wqkv [h*192+j][k]
  const int T1 = T0 + 384 * 384;        // WoT  [n][k]
  const int T2 = T1 + 1536 * 384;       // W1T  [n][k]
  const int T3 = T2 + 384 * 1536;       // W2T  [n][k]
  for (int i = blockIdx.x * blockDim.x + threadIdx.x; i < T3; i += gridDim.x * blockDim.x) {
    float v;
    if (i < T0) {
      int n = i / 384, k = i % 384;
      int hh = n / 192, j = n % 192;
      const float* W = (j < 64) ? Wq : (j < 128) ? Wk : Wv;
      int d = (j < 64) ? j : (j < 128) ? j - 64 : j - 128;
      v = W[((size_t)hh * 384 + k) * 64 + d];
    } else if (i < T1) {
      int i2 = i - T0; int n = i2 / 384, k = i2 % 384;
      v = Wo[(size_t)k * 384 + n];
    } else if (i < T2) {
      int i2 = i - T1; int n = i2 / 384, k = i2 % 384;
      v = W1[(size_t)k * 1536 + n];
    } else {
      int i2 = i - T2; int n = i2 / 1536, k = i2 % 1536;
      v = W2[(size_t)k * 384 + n];
    }
    ws[i] = f2bf(v);
  }
}

// ---- kernel A: LN1 + attention + per-head proj accumulation + residual -> x2 (=d_out, fp32)
__global__ __launch_bounds__(256, 2)
void attn_fwd(const float* __restrict__ x,
              const float* __restrict__ ln1g, const float* __restrict__ ln1b,
              const float* __restrict__ bo,
              const unsigned short* __restrict__ Wqkv,
              const unsigned short* __restrict__ WoT,
              float* __restrict__ x2) {
  __shared__ unsigned short sXN[TT * LDX];       // xn1 (bf16)
  __shared__ unsigned short sHEAD[3 * TT * LDH]; // q | k (later att_h) | vT
  unsigned short* sQ = sHEAD;                    // q [t][d]; later P [t][s]
  unsigned short* sK = sHEAD + TT * LDH;         // k [s][d]; later att_h [t][d]
  unsigned short* sV = sHEAD + 2 * TT * LDH;     // vT [d][s]

  const int b = blockIdx.x;
  const int tid = threadIdx.x;
  const int wv = tid >> 6;
  const int ln = tid & 63;
  const int l16 = ln & 15;
  const int lg = ln >> 4;
  const float* xb = x + (size_t)b * TT * CC;
  const f32x4 Z4 = {0.f, 0.f, 0.f, 0.f};

  // ---------- LN1 ----------
  for (int r = wv * 16; r < wv * 16 + 16; ++r) {
    float v[6], s = 0.f, sq = 0.f;
#pragma unroll
    for (int j = 0; j < 6; ++j) { v[j] = xb[r * CC + ln + 64 * j]; s += v[j]; sq += v[j] * v[j]; }
#pragma unroll
    for (int off = 32; off; off >>= 1) { s += __shfl_xor(s, off); sq += __shfl_xor(sq, off); }
    float mu = s * (1.f / CC);
    float rs = rsqrtf(sq * (1.f / CC) - mu * mu + 1e-5f);
#pragma unroll
    for (int j = 0; j < 6; ++j) {
      int c = ln + 64 * j;
      sXN[r * LDX + c] = f2bf((v[j] - mu) * rs * ln1g[c] + ln1b[c]);
    }
  }
  __syncthreads();

  // persistent proj accumulator (rows m*16+lg*4+rg, cols wv*96+c*16+l16)
  f32x4 pacc[4][6];
#pragma unroll
  for (int m = 0; m < 4; ++m)
#pragma unroll
    for (int c = 0; c < 6; ++c) pacc[m][c] = Z4;

  // Wo row pointers for this wave's 6 output c-tiles (reused every head)
  const unsigned short* prow[6];
#pragma unroll
  for (int c = 0; c < 6; ++c)
    prow[c] = WoT + (size_t)(wv * 96 + c * 16 + l16) * CC + 8 * lg;

  for (int h = 0; h < NH; ++h) {
    // ----- qkv = xn @ Wh : 64 x 192, wave stripe cols [48*wv, 48*wv+48)
    const unsigned short* wrow[3];
#pragma unroll
    for (int c = 0; c < 3; ++c)
      wrow[c] = Wqkv + (size_t)(h * 192 + wv * 48 + c * 16 + l16) * CC + 8 * lg;

    f32x4 qacc[4][3];
#pragma unroll
    for (int m = 0; m < 4; ++m)
#pragma unroll
      for (int c = 0; c < 3; ++c) qacc[m][c] = Z4;

    // depth-2 B prefetch pipeline
    bf16x8 bpre[2][3];
#pragma unroll
    for (int c = 0; c < 3; ++c) bpre[0][c] = ld8(wrow[c] + 0);
#pragma unroll
    for (int c = 0; c < 3; ++c) bpre[1][c] = ld8(wrow[c] + 32);
#pragma unroll
    for (int kk = 0; kk < CC; kk += 32) {
      const int slot = (kk >> 5) & 1;
      bf16x8 bcur[3];
#pragma unroll
      for (int c = 0; c < 3; ++c) bcur[c] = bpre[slot][c];
      if (kk + 64 < CC) {
#pragma unroll
        for (int c = 0; c < 3; ++c) bpre[slot][c] = ld8(wrow[c] + kk + 64);
      }
      bf16x8 a[4];
#pragma unroll
      for (int m = 0; m < 4; ++m)
        a[m] = ld8(&sXN[(m * 16 + l16) * LDX + kk + 8 * lg]);
      __builtin_amdgcn_s_setprio(1);
#pragma unroll
      for (int c = 0; c < 3; ++c)
#pragma unroll
        for (int m = 0; m < 4; ++m) qacc[m][c] = MFMA(a[m], bcur[c], qacc[m][c]);
      __builtin_amdgcn_s_setprio(0);
    }
    __syncthreads();  // B1: prior head's proj reads of sK / PV reads of sV done
    // scatter: q [t][d], k [s][d], vT [d][s]
#pragma unroll
    for (int m = 0; m < 4; ++m)
#pragma unroll
      for (int c = 0; c < 3; ++c) {
        int n = wv * 48 + c * 16 + l16;
#pragma unroll
        for (int rg = 0; rg < 4; ++rg) {
          int t = m * 16 + lg * 4 + rg;
          unsigned short bv = f2bf(qacc[m][c][rg]);
          if (n < 64) sQ[t * LDH + n] = bv;
          else if (n < 128) sK[t * LDH + (n - 64)] = bv;
          else sV[(n - 128) * LDH + t] = bv;
        }
      }
    __syncthreads();  // B2

    // ----- S = q.kT for this wave's 16 rows
    f32x4 sacc[4];
#pragma unroll
    for (int c = 0; c < 4; ++c) sacc[c] = Z4;
#pragma unroll
    for (int kk = 0; kk < 64; kk += 32) {
      bf16x8 a = ld8(&sQ[(wv * 16 + l16) * LDH + kk + 8 * lg]);
#pragma unroll
      for (int c = 0; c < 4; ++c) {
        bf16x8 bb = ld8(&sK[(c * 16 + l16) * LDH + kk + 8 * lg]);
        sacc[c] = MFMA(a, bb, sacc[c]);
      }
    }
    // causal softmax (rows in 16-lane groups), P overlays q (own rows)
#pragma unroll
    for (int rg = 0; rg < 4; ++rg) {
      int row = wv * 16 + lg * 4 + rg;
      float e[4], mx = -1e30f;
#pragma unroll
      for (int c = 0; c < 4; ++c) {
        int col = c * 16 + l16;
        float vv = sacc[c][rg] * 0.125f;
        e[c] = (col <= row) ? vv : -1e30f;
        mx = fmaxf(mx, e[c]);
      }
#pragma unroll
      for (int off = 8; off; off >>= 1) mx = fmaxf(mx, __shfl_xor(mx, off));
      float sum = 0.f;
#pragma unroll
      for (int c = 0; c < 4; ++c) {
        int col = c * 16 + l16;
        e[c] = (col <= row) ? __expf(e[c] - mx) : 0.f;
        sum += e[c];
      }
#pragma unroll
      for (int off = 8; off; off >>= 1) sum += __shfl_xor(sum, off);
      float inv = 1.f / sum;
#pragma unroll
      for (int c = 0; c < 4; ++c)
        sQ[row * LDH + c * 16 + l16] = f2bf(e[c] * inv);
    }

    // Preload ALL Wo B-frags for this head NOW (12 x 16B); latency hides under PV.
    bf16x8 pb[2][6];
#pragma unroll
    for (int s2 = 0; s2 < 2; ++s2)
#pragma unroll
      for (int c = 0; c < 6; ++c)
        pb[s2][c] = ld8(prow[c] + h * 64 + 32 * s2);

    // ----- out_h = P @ V (own 16 rows); same-wave LDS ops are ordered
    f32x4 oacc[4];
#pragma unroll
    for (int c = 0; c < 4; ++c) oacc[c] = Z4;
#pragma unroll
    for (int kk = 0; kk < 64; kk += 32) {
      bf16x8 a = ld8(&sQ[(wv * 16 + l16) * LDH + kk + 8 * lg]);
#pragma unroll
      for (int c = 0; c < 4; ++c) {
        bf16x8 bb = ld8(&sV[(c * 16 + l16) * LDH + kk + 8 * lg]);
        oacc[c] = MFMA(a, bb, oacc[c]);
      }
    }
    __syncthreads();  // B3: all waves done reading sK (S phase)
    // stage att_h into sK region [t][d]
#pragma unroll
    for (int c = 0; c < 4; ++c)
#pragma unroll
      for (int rg = 0; rg < 4; ++rg) {
        int t = wv * 16 + lg * 4 + rg;
        sK[t * LDH + c * 16 + l16] = f2bf(oacc[c][rg]);
      }
    __syncthreads();  // B4: att_h visible

    // ----- proj accumulate: pacc += att_h @ WoT[:, h*64 .. h*64+63] (B already in regs)
    __builtin_amdgcn_s_setprio(1);
#pragma unroll
    for (int kk = 0; kk < 64; kk += 32) {
      const int slot = kk >> 5;
      bf16x8 a[4];
#pragma unroll
      for (int m = 0; m < 4; ++m)
        a[m] = ld8(&sK[(m * 16 + l16) * LDH + kk + 8 * lg]);
#pragma unroll
      for (int c = 0; c < 6; ++c)
#pragma unroll
        for (int m = 0; m < 4; ++m) pacc[m][c] = MFMA(a[m], pb[slot][c], pacc[m][c]);
    }
    __builtin_amdgcn_s_setprio(0);
  }

  // ---------- x2 = x + proj + bo (fp32, to d_out) ----------
  float* xo = x2 + (size_t)b * TT * CC;
#pragma unroll
  for (int m = 0; m < 4; ++m)
#pragma unroll
    for (int c = 0; c < 6; ++c) {
      int n = wv * 96 + c * 16 + l16;
      float bov = bo[n];
#pragma unroll
      for (int rg = 0; rg < 4; ++rg) {
        int t = m * 16 + lg * 4 + rg;
        xo[t * CC + n] = xb[t * CC + n] + pacc[m][c][rg] + bov;
      }
    }
}

// ---- kernel B: LN2 + MLP + residual; x2 lives in d_out, overwritten in place ----
__global__ __launch_bounds__(256, 2)
void mlp_fwd(const float* __restrict__ ln2g, const float* __restrict__ ln2b,
             const float* __restrict__ b1, const float* __restrict__ b2,
             const unsigned short* __restrict__ W1T,
             const unsigned short* __restrict__ W2T,
             float* xo) {
  __shared__ unsigned short sXN[TT * LDX];  // xn2 (bf16)
  __shared__ unsigned short sH[TT * LDM];   // relu(h) chunk (bf16)

  const int b = blockIdx.x;
  const int tid = threadIdx.x;
  const int wv = tid >> 6;
  const int ln = tid & 63;
  const int l16 = ln & 15;
  const int lg = ln >> 4;
  float* xb = xo + (size_t)b * TT * CC;  // x2 rows (read-then-overwrite)
  const f32x4 Z4 = {0.f, 0.f, 0.f, 0.f};

  // ---------- LN2 ----------
  for (int r = wv * 16; r < wv * 16 + 16; ++r) {
    float v[6], s = 0.f, sq = 0.f;
#pragma unroll
    for (int j = 0; j < 6; ++j) { v[j] = xb[r * CC + ln + 64 * j]; s += v[j]; sq += v[j] * v[j]; }
#pragma unroll
    for (int off = 32; off; off >>= 1) { s += __shfl_xor(s, off); sq += __shfl_xor(sq, off); }
    float mu = s * (1.f / CC);
    float rs = rsqrtf(sq * (1.f / CC) - mu * mu + 1e-5f);
#pragma unroll
    for (int j = 0; j < 6; ++j) {
      int c = ln + 64 * j;
      sXN[r * LDX + c] = f2bf((v[j] - mu) * rs * ln2g[c] + ln2b[c]);
    }
  }
  __syncthreads();

  // ---------- MLP: 8 chunks of 192 hidden cols; persistent out acc ----------
  f32x4 macc[4][6];
#pragma unroll
  for (int m = 0; m < 4; ++m)
#pragma unroll
    for (int c = 0; c < 6; ++c) macc[m][c] = Z4;

  // W2 row pointers for this wave's 6 output c-tiles
  const unsigned short* w2row[6];
#pragma unroll
  for (int c = 0; c < 6; ++c)
    w2row[c] = W2T + (size_t)(wv * 96 + c * 16 + l16) * HID + 8 * lg;

  for (int ch = 0; ch < 8; ++ch) {
    // ----- GEMM1: h = relu(xn2 @ W1 + b1), wave stripe 48 cols of 192-chunk
    const unsigned short* w1row[3];
#pragma unroll
    for (int c = 0; c < 3; ++c)
      w1row[c] = W1T + (size_t)(ch * 192 + wv * 48 + c * 16 + l16) * CC + 8 * lg;

    f32x4 hacc[4][3];
#pragma unroll
    for (int m = 0; m < 4; ++m)
#pragma unroll
      for (int c = 0; c < 3; ++c) hacc[m][c] = Z4;

    bf16x8 bpre[2][3];
#pragma unroll
    for (int c = 0; c < 3; ++c) bpre[0][c] = ld8(w1row[c] + 0);
#pragma unroll
    for (int c = 0; c < 3; ++c) bpre[1][c] = ld8(w1row[c] + 32);
#pragma unroll
    for (int kk = 0; kk < CC; kk += 32) {
      const int slot = (kk >> 5) & 1;
      bf16x8 bcur[3];
#pragma unroll
      for (int c = 0; c < 3; ++c) bcur[c] = bpre[slot][c];
      if (kk + 64 < CC) {
#pragma unroll
        for (int c = 0; c < 3; ++c) bpre[slot][c] = ld8(w1row[c] + kk + 64);
      }
      bf16x8 a[4];
#pragma unroll
      for (int m = 0; m < 4; ++m)
        a[m] = ld8(&sXN[(m * 16 + l16) * LDX + kk + 8 * lg]);
      __builtin_amdgcn_s_setprio(1);
#pragma unroll
      for (int c = 0; c < 3; ++c)
#pragma unroll
        for (int m = 0; m < 4; ++m) hacc[m][c] = MFMA(a[m], bcur[c], hacc[m][c]);
      __builtin_amdgcn_s_setprio(0);
    }
    __syncthreads();  // prior GEMM2 reads of sH done
#pragma unroll
    for (int m = 0; m < 4; ++m)
#pragma unroll
      for (int c = 0; c < 3; ++c) {
        int nl = wv * 48 + c * 16 + l16;
        float b1v = b1[ch * 192 + nl];
#pragma unroll
        for (int rg = 0; rg < 4; ++rg) {
          int t = m * 16 + lg * 4 + rg;
          sH[t * LDM + nl] = f2bf(fmaxf(hacc[m][c][rg] + b1v, 0.f));
        }
      }
    __syncthreads();  // h chunk visible

    // ----- GEMM2: macc += h @ W2[ch-slice], depth-1 B prefetch
    bf16x8 b2p[6];
#pragma unroll
    for (int c = 0; c < 6; ++c) b2p[c] = ld8(w2row[c] + ch * 192);
#pragma unroll
    for (int kk = 0; kk < 192; kk += 32) {
      bf16x8 b2n[6];
      if (kk + 32 < 192) {
#pragma unroll
        for (int c = 0; c < 6; ++c) b2n[c] = ld8(w2row[c] + ch * 192 + kk + 32);
      }
      bf16x8 a[4];
#pragma unroll
      for (int m = 0; m < 4; ++m)
        a[m] = ld8(&sH[(m * 16 + l16) * LDM + kk + 8 * lg]);
      __builtin_amdgcn_s_setprio(1);
#pragma unroll
      for (int c = 0; c < 6; ++c)
#pragma unroll
        for (int m = 0; m < 4; ++m) macc[m][c] = MFMA(a[m], b2p[c], macc[m][c]);
      __builtin_amdgcn_s_setprio(0);
      if (kk + 32 < 192) {
#pragma unroll
        for (int c = 0; c < 6; ++c) b2p[c] = b2n[c];
      }
    }
  }
  // ---------- out = x2 + mlp + b2 (read-before-write, same buffer) ----------
#pragma unroll
  for (int m = 0; m < 4; ++m)
#pragma unroll
    for (int c = 0; c < 6; ++c) {
      int n = wv * 96 + c * 16 + l16;
      float b2v = b2[n];
#pragma unroll
      for (int rg = 0; rg < 4; ++rg) {
        int t = m * 16 + lg * 4 + rg;
        size_t idx = (size_t)t * CC + n;
        float x2v = xb[idx];
        xb[idx] = x2v + macc[m][c][rg] + b2v;
      }
    }
}

extern "C" void kernel_launch(void* const* d_in, const int* in_sizes, int n_in,
                              void* d_out, int out_size, void* d_ws, size_t ws_size,
                              hipStream_t stream) {
  const float* x    = (const float*)d_in[0];
  const float* ln1g = (const float*)d_in[1];
  const float* ln1b = (const float*)d_in[2];
  const float* Wq   = (const float*)d_in[3];
  const float* Wk   = (const float*)d_in[4];
  const float* Wv   = (const float*)d_in[5];
  const float* Wo   = (const float*)d_in[6];
  const float* bo   = (const float*)d_in[7];
  const float* ln2g = (const float*)d_in[8];
  const float* ln2b = (const float*)d_in[9];
  const float* W1   = (const float*)d_in[10];
  const float* b1   = (const float*)d_in[11];
  const float* W2   = (const float*)d_in[12];
  const float* b2   = (const float*)d_in[13];
  unsigned short* ws = (unsigned short*)d_ws;

  const size_t need = (size_t)(1152 * 384 + 384 * 384 + 1536 * 384 + 384 * 1536) * 2;
  if (ws_size < need) return;

  hipLaunchKernelGGL(prep_w, dim3(1024), dim3(256), 0, stream, Wq, Wk, Wv, Wo, W1, W2, ws);

  const unsigned short* Wqkv = ws;
  const unsigned short* WoT  = ws + 1152 * 384;
  const unsigned short* W1T  = WoT + 384 * 384;
  const unsigned short* W2T  = W1T + 1536 * 384;
  int nblk = in_sizes[0] / (TT * CC);

  hipLaunchKernelGGL(attn_fwd, dim3(nblk), dim3(256), 0, stream,
                     x, ln1g, ln1b, bo, Wqkv, WoT, (float*)d_out);
  hipLaunchKernelGGL(mlp_fwd, dim3(nblk), dim3(256), 0, stream,
                     ln2g, ln2b, b1, b2, W1T, W2T, (float*)d_out);
}

// Round 5
// 512.231 us; speedup vs baseline: 1.4625x; 1.0005x over previous
//
#include <hip/hip_runtime.h>

#define TT 64
#define CC 384
#define NH 6
#define HID 1536
#define LDX 392   // padded cols for 64x384 bf16 tiles
#define LDH 72    // head tiles (144B stride)
#define LDM 200   // mlp h-chunk (192+8)

typedef __bf16 bf16x8 __attribute__((ext_vector_type(8)));
typedef float f32x4 __attribute__((ext_vector_type(4)));
typedef unsigned short us8 __attribute__((ext_vector_type(8)));

#define MFMA(a, b, c) __builtin_amdgcn_mfma_f32_16x16x32_bf16(a, b, c, 0, 0, 0)

static __device__ __forceinline__ unsigned short f2bf(float f) {
  unsigned u = __builtin_bit_cast(unsigned, f);
  u += 0x7FFFu + ((u >> 16) & 1u);
  return (unsigned short)(u >> 16);
}
static __device__ __forceinline__ float bf2f(unsigned short h) {
  unsigned u = ((unsigned)h) << 16;
  return __builtin_bit_cast(float, u);
}
static __device__ __forceinline__ bf16x8 ld8(const unsigned short* p) {
  return __builtin_bit_cast(bf16x8, *reinterpret_cast<const us8*>(p));
}

// ---- weight prep: fp32 -> bf16, transposed to [n][k] for MFMA B-frags ----
__global__ void prep_w(const float* __restrict__ Wq, const float* __restrict__ Wk,
                       const float* __restrict__ Wv, const float* __restrict__ Wo,
                       const float* __restrict__ W1, const float* __restrict__ W2,
                       unsigned short* __restrict__ ws) {
  const int T0 = 1152 * 384;            // Wqkv [h*192+j][k]
  const int T1 = T0 + 384 * 384;        // WoT  [n][k]
  const int T2 = T1 + 1536 * 384;       // W1T  [n][k]
  const int T3 = T2 + 384 * 1536;       // W2T  [n][k]
  for (int i = blockIdx.x * blockDim.x + threadIdx.x; i < T3; i += gridDim.x * blockDim.x) {
    float v;
    if (i < T0) {
      int n = i / 384, k = i % 384;
      int hh = n / 192, j = n % 192;
      const float* W = (j < 64) ? Wq : (j < 128) ? Wk : Wv;
      int d = (j < 64) ? j : (j < 128) ? j - 64 : j - 128;
      v = W[((size_t)hh * 384 + k) * 64 + d];
    } else if (i < T1) {
      int i2 = i - T0; int n = i2 / 384, k = i2 % 384;
      v = Wo[(size_t)k * 384 + n];
    } else if (i < T2) {
      int i2 = i - T1; int n = i2 / 384, k = i2 % 384;
      v = W1[(size_t)k * 1536 + n];
    } else {
      int i2 = i - T2; int n = i2 / 1536, k = i2 % 1536;
      v = W2[(size_t)k * 384 + n];
    }
    ws[i] = f2bf(v);
  }
}

// ---- kernel A: LN1 + attention + per-head proj accumulation + residual -> x2 (=d_out, fp32)
__global__ __launch_bounds__(256, 2)
void attn_fwd(const float* __restrict__ x,
              const float* __restrict__ ln1g, const float* __restrict__ ln1b,
              const float* __restrict__ bo,
              const unsigned short* __restrict__ Wqkv,
              const unsigned short* __restrict__ WoT,
              float* __restrict__ x2) {
  __shared__ unsigned short sXN[TT * LDX];       // xn1 (bf16)
  __shared__ unsigned short sHEAD[3 * TT * LDH]; // q | k (later att_h) | vT
  unsigned short* sQ = sHEAD;                    // q [t][d]; later P [t][s]
  unsigned short* sK = sHEAD + TT * LDH;         // k [s][d]; later att_h [t][d]
  unsigned short* sV = sHEAD + 2 * TT * LDH;     // vT [d][s]

  const int b = blockIdx.x;
  const int tid = threadIdx.x;
  const int wv = tid >> 6;
  const int ln = tid & 63;
  const int l16 = ln & 15;
  const int lg = ln >> 4;
  const float* xb = x + (size_t)b * TT * CC;
  const f32x4 Z4 = {0.f, 0.f, 0.f, 0.f};

  // ---------- LN1 (rolled: keep code small, I$-resident) ----------
#pragma unroll 1
  for (int r = wv * 16; r < wv * 16 + 16; ++r) {
    float v[6], s = 0.f, sq = 0.f;
#pragma unroll
    for (int j = 0; j < 6; ++j) { v[j] = xb[r * CC + ln + 64 * j]; s += v[j]; sq += v[j] * v[j]; }
#pragma unroll
    for (int off = 32; off; off >>= 1) { s += __shfl_xor(s, off); sq += __shfl_xor(sq, off); }
    float mu = s * (1.f / CC);
    float rs = rsqrtf(sq * (1.f / CC) - mu * mu + 1e-5f);
#pragma unroll
    for (int j = 0; j < 6; ++j) {
      int c = ln + 64 * j;
      sXN[r * LDX + c] = f2bf((v[j] - mu) * rs * ln1g[c] + ln1b[c]);
    }
  }
  __syncthreads();

  // persistent proj accumulator (rows m*16+lg*4+rg, cols wv*96+c*16+l16)
  f32x4 pacc[4][6];
#pragma unroll
  for (int m = 0; m < 4; ++m)
#pragma unroll
    for (int c = 0; c < 6; ++c) pacc[m][c] = Z4;

  // Wo row pointers for this wave's 6 output c-tiles (reused every head)
  const unsigned short* prow[6];
#pragma unroll
  for (int c = 0; c < 6; ++c)
    prow[c] = WoT + (size_t)(wv * 96 + c * 16 + l16) * CC + 8 * lg;

  // ---------- head loop: ROLLED (6x code reuse in I$) ----------
#pragma unroll 1
  for (int h = 0; h < NH; ++h) {
    // ----- qkv = xn @ Wh : 64 x 192, wave stripe cols [48*wv, 48*wv+48)
    const unsigned short* wrow[3];
#pragma unroll
    for (int c = 0; c < 3; ++c)
      wrow[c] = Wqkv + (size_t)(h * 192 + wv * 48 + c * 16 + l16) * CC + 8 * lg;

    f32x4 qacc[4][3];
#pragma unroll
    for (int m = 0; m < 4; ++m)
#pragma unroll
      for (int c = 0; c < 3; ++c) qacc[m][c] = Z4;

    // depth-2 B prefetch pipeline
    bf16x8 bpre[2][3];
#pragma unroll
    for (int c = 0; c < 3; ++c) bpre[0][c] = ld8(wrow[c] + 0);
#pragma unroll
    for (int c = 0; c < 3; ++c) bpre[1][c] = ld8(wrow[c] + 32);
#pragma unroll
    for (int kk = 0; kk < CC; kk += 32) {
      const int slot = (kk >> 5) & 1;
      bf16x8 bcur[3];
#pragma unroll
      for (int c = 0; c < 3; ++c) bcur[c] = bpre[slot][c];
      if (kk + 64 < CC) {
#pragma unroll
        for (int c = 0; c < 3; ++c) bpre[slot][c] = ld8(wrow[c] + kk + 64);
      }
      bf16x8 a[4];
#pragma unroll
      for (int m = 0; m < 4; ++m)
        a[m] = ld8(&sXN[(m * 16 + l16) * LDX + kk + 8 * lg]);
      __builtin_amdgcn_s_setprio(1);
#pragma unroll
      for (int c = 0; c < 3; ++c)
#pragma unroll
        for (int m = 0; m < 4; ++m) qacc[m][c] = MFMA(a[m], bcur[c], qacc[m][c]);
      __builtin_amdgcn_s_setprio(0);
    }
    __syncthreads();  // B1: prior head's proj reads of sK / PV reads of sV done
    // scatter: q [t][d], k [s][d], vT [d][s]
#pragma unroll
    for (int m = 0; m < 4; ++m)
#pragma unroll
      for (int c = 0; c < 3; ++c) {
        int n = wv * 48 + c * 16 + l16;
#pragma unroll
        for (int rg = 0; rg < 4; ++rg) {
          int t = m * 16 + lg * 4 + rg;
          unsigned short bv = f2bf(qacc[m][c][rg]);
          if (n < 64) sQ[t * LDH + n] = bv;
          else if (n < 128) sK[t * LDH + (n - 64)] = bv;
          else sV[(n - 128) * LDH + t] = bv;
        }
      }
    __syncthreads();  // B2

    // ----- S = q.kT for this wave's 16 rows
    f32x4 sacc[4];
#pragma unroll
    for (int c = 0; c < 4; ++c) sacc[c] = Z4;
#pragma unroll
    for (int kk = 0; kk < 64; kk += 32) {
      bf16x8 a = ld8(&sQ[(wv * 16 + l16) * LDH + kk + 8 * lg]);
#pragma unroll
      for (int c = 0; c < 4; ++c) {
        bf16x8 bb = ld8(&sK[(c * 16 + l16) * LDH + kk + 8 * lg]);
        sacc[c] = MFMA(a, bb, sacc[c]);
      }
    }
    // causal softmax (rows in 16-lane groups), P overlays q (own rows)
#pragma unroll
    for (int rg = 0; rg < 4; ++rg) {
      int row = wv * 16 + lg * 4 + rg;
      float e[4], mx = -1e30f;
#pragma unroll
      for (int c = 0; c < 4; ++c) {
        int col = c * 16 + l16;
        float vv = sacc[c][rg] * 0.125f;
        e[c] = (col <= row) ? vv : -1e30f;
        mx = fmaxf(mx, e[c]);
      }
#pragma unroll
      for (int off = 8; off; off >>= 1) mx = fmaxf(mx, __shfl_xor(mx, off));
      float sum = 0.f;
#pragma unroll
      for (int c = 0; c < 4; ++c) {
        int col = c * 16 + l16;
        e[c] = (col <= row) ? __expf(e[c] - mx) : 0.f;
        sum += e[c];
      }
#pragma unroll
      for (int off = 8; off; off >>= 1) sum += __shfl_xor(sum, off);
      float inv = 1.f / sum;
#pragma unroll
      for (int c = 0; c < 4; ++c)
        sQ[row * LDH + c * 16 + l16] = f2bf(e[c] * inv);
    }

    // Preload ALL Wo B-frags for this head NOW (12 x 16B); latency hides under PV.
    bf16x8 pb[2][6];
#pragma unroll
    for (int s2 = 0; s2 < 2; ++s2)
#pragma unroll
      for (int c = 0; c < 6; ++c)
        pb[s2][c] = ld8(prow[c] + h * 64 + 32 * s2);

    // ----- out_h = P @ V (own 16 rows); same-wave LDS ops are ordered
    f32x4 oacc[4];
#pragma unroll
    for (int c = 0; c < 4; ++c) oacc[c] = Z4;
#pragma unroll
    for (int kk = 0; kk < 64; kk += 32) {
      bf16x8 a = ld8(&sQ[(wv * 16 + l16) * LDH + kk + 8 * lg]);
#pragma unroll
      for (int c = 0; c < 4; ++c) {
        bf16x8 bb = ld8(&sV[(c * 16 + l16) * LDH + kk + 8 * lg]);
        oacc[c] = MFMA(a, bb, oacc[c]);
      }
    }
    __syncthreads();  // B3: all waves done reading sK (S phase)
    // stage att_h into sK region [t][d]
#pragma unroll
    for (int c = 0; c < 4; ++c)
#pragma unroll
      for (int rg = 0; rg < 4; ++rg) {
        int t = wv * 16 + lg * 4 + rg;
        sK[t * LDH + c * 16 + l16] = f2bf(oacc[c][rg]);
      }
    __syncthreads();  // B4: att_h visible

    // ----- proj accumulate: pacc += att_h @ WoT[:, h*64 .. h*64+63] (B already in regs)
    __builtin_amdgcn_s_setprio(1);
#pragma unroll
    for (int kk = 0; kk < 64; kk += 32) {
      const int slot = kk >> 5;
      bf16x8 a[4];
#pragma unroll
      for (int m = 0; m < 4; ++m)
        a[m] = ld8(&sK[(m * 16 + l16) * LDH + kk + 8 * lg]);
#pragma unroll
      for (int c = 0; c < 6; ++c)
#pragma unroll
        for (int m = 0; m < 4; ++m) pacc[m][c] = MFMA(a[m], pb[slot][c], pacc[m][c]);
    }
    __builtin_amdgcn_s_setprio(0);
  }

  // ---------- x2 = x + proj + bo (fp32, to d_out) ----------
  float* xo = x2 + (size_t)b * TT * CC;
#pragma unroll
  for (int m = 0; m < 4; ++m)
#pragma unroll
    for (int c = 0; c < 6; ++c) {
      int n = wv * 96 + c * 16 + l16;
      float bov = bo[n];
#pragma unroll
      for (int rg = 0; rg < 4; ++rg) {
        int t = m * 16 + lg * 4 + rg;
        xo[t * CC + n] = xb[t * CC + n] + pacc[m][c][rg] + bov;
      }
    }
}

// ---- kernel B: LN2 + MLP + residual; x2 lives in d_out, overwritten in place ----
__global__ __launch_bounds__(256, 2)
void mlp_fwd(const float* __restrict__ ln2g, const float* __restrict__ ln2b,
             const float* __restrict__ b1, const float* __restrict__ b2,
             const unsigned short* __restrict__ W1T,
             const unsigned short* __restrict__ W2T,
             float* xo) {
  __shared__ unsigned short sXN[TT * LDX];  // xn2 (bf16)
  __shared__ unsigned short sH[TT * LDM];   // relu(h) chunk (bf16)

  const int b = blockIdx.x;
  const int tid = threadIdx.x;
  const int wv = tid >> 6;
  const int ln = tid & 63;
  const int l16 = ln & 15;
  const int lg = ln >> 4;
  float* xb = xo + (size_t)b * TT * CC;  // x2 rows (read-then-overwrite)
  const f32x4 Z4 = {0.f, 0.f, 0.f, 0.f};

  // ---------- LN2 (rolled) ----------
#pragma unroll 1
  for (int r = wv * 16; r < wv * 16 + 16; ++r) {
    float v[6], s = 0.f, sq = 0.f;
#pragma unroll
    for (int j = 0; j < 6; ++j) { v[j] = xb[r * CC + ln + 64 * j]; s += v[j]; sq += v[j] * v[j]; }
#pragma unroll
    for (int off = 32; off; off >>= 1) { s += __shfl_xor(s, off); sq += __shfl_xor(sq, off); }
    float mu = s * (1.f / CC);
    float rs = rsqrtf(sq * (1.f / CC) - mu * mu + 1e-5f);
#pragma unroll
    for (int j = 0; j < 6; ++j) {
      int c = ln + 64 * j;
      sXN[r * LDX + c] = f2bf((v[j] - mu) * rs * ln2g[c] + ln2b[c]);
    }
  }
  __syncthreads();

  // ---------- MLP: 8 chunks of 192 hidden cols; chunk loop ROLLED (8x I$ reuse) ----------
  f32x4 macc[4][6];
#pragma unroll
  for (int m = 0; m < 4; ++m)
#pragma unroll
    for (int c = 0; c < 6; ++c) macc[m][c] = Z4;

  // W2 row pointers for this wave's 6 output c-tiles
  const unsigned short* w2row[6];
#pragma unroll
  for (int c = 0; c < 6; ++c)
    w2row[c] = W2T + (size_t)(wv * 96 + c * 16 + l16) * HID + 8 * lg;

#pragma unroll 1
  for (int ch = 0; ch < 8; ++ch) {
    // ----- GEMM1: h = relu(xn2 @ W1 + b1), wave stripe 48 cols of 192-chunk
    const unsigned short* w1row[3];
#pragma unroll
    for (int c = 0; c < 3; ++c)
      w1row[c] = W1T + (size_t)(ch * 192 + wv * 48 + c * 16 + l16) * CC + 8 * lg;

    f32x4 hacc[4][3];
#pragma unroll
    for (int m = 0; m < 4; ++m)
#pragma unroll
      for (int c = 0; c < 3; ++c) hacc[m][c] = Z4;

    bf16x8 bpre[2][3];
#pragma unroll
    for (int c = 0; c < 3; ++c) bpre[0][c] = ld8(w1row[c] + 0);
#pragma unroll
    for (int c = 0; c < 3; ++c) bpre[1][c] = ld8(w1row[c] + 32);
#pragma unroll
    for (int kk = 0; kk < CC; kk += 32) {
      const int slot = (kk >> 5) & 1;
      bf16x8 bcur[3];
#pragma unroll
      for (int c = 0; c < 3; ++c) bcur[c] = bpre[slot][c];
      if (kk + 64 < CC) {
#pragma unroll
        for (int c = 0; c < 3; ++c) bpre[slot][c] = ld8(w1row[c] + kk + 64);
      }
      bf16x8 a[4];
#pragma unroll
      for (int m = 0; m < 4; ++m)
        a[m] = ld8(&sXN[(m * 16 + l16) * LDX + kk + 8 * lg]);
      __builtin_amdgcn_s_setprio(1);
#pragma unroll
      for (int c = 0; c < 3; ++c)
#pragma unroll
        for (int m = 0; m < 4; ++m) hacc[m][c] = MFMA(a[m], bcur[c], hacc[m][c]);
      __builtin_amdgcn_s_setprio(0);
    }
    __syncthreads();  // prior GEMM2 reads of sH done
#pragma unroll
    for (int m = 0; m < 4; ++m)
#pragma unroll
      for (int c = 0; c < 3; ++c) {
        int nl = wv * 48 + c * 16 + l16;
        float b1v = b1[ch * 192 + nl];
#pragma unroll
        for (int rg = 0; rg < 4; ++rg) {
          int t = m * 16 + lg * 4 + rg;
          sH[t * LDM + nl] = f2bf(fmaxf(hacc[m][c][rg] + b1v, 0.f));
        }
      }
    __syncthreads();  // h chunk visible

    // ----- GEMM2: macc += h @ W2[ch-slice], depth-1 B prefetch
    bf16x8 b2p[6];
#pragma unroll
    for (int c = 0; c < 6; ++c) b2p[c] = ld8(w2row[c] + ch * 192);
#pragma unroll
    for (int kk = 0; kk < 192; kk += 32) {
      bf16x8 b2n[6];
      if (kk + 32 < 192) {
#pragma unroll
        for (int c = 0; c < 6; ++c) b2n[c] = ld8(w2row[c] + ch * 192 + kk + 32);
      }
      bf16x8 a[4];
#pragma unroll
      for (int m = 0; m < 4; ++m)
        a[m] = ld8(&sH[(m * 16 + l16) * LDM + kk + 8 * lg]);
      __builtin_amdgcn_s_setprio(1);
#pragma unroll
      for (int c = 0; c < 6; ++c)
#pragma unroll
        for (int m = 0; m < 4; ++m) macc[m][c] = MFMA(a[m], b2p[c], macc[m][c]);
      __builtin_amdgcn_s_setprio(0);
      if (kk + 32 < 192) {
#pragma unroll
        for (int c = 0; c < 6; ++c) b2p[c] = b2n[c];
      }
    }
  }
  // ---------- out = x2 + mlp + b2 (read-before-write, same buffer) ----------
#pragma unroll
  for (int m = 0; m < 4; ++m)
#pragma unroll
    for (int c = 0; c < 6; ++c) {
      int n = wv * 96 + c * 16 + l16;
      float b2v = b2[n];
#pragma unroll
      for (int rg = 0; rg < 4; ++rg) {
        int t = m * 16 + lg * 4 + rg;
        size_t idx = (size_t)t * CC + n;
        float x2v = xb[idx];
        xb[idx] = x2v + macc[m][c][rg] + b2v;
      }
    }
}

extern "C" void kernel_launch(void* const* d_in, const int* in_sizes, int n_in,
                              void* d_out, int out_size, void* d_ws, size_t ws_size,
                              hipStream_t stream) {
  const float* x    = (const float*)d_in[0];
  const float* ln1g = (const float*)d_in[1];
  const float* ln1b = (const float*)d_in[2];
  const float* Wq   = (const float*)d_in[3];
  const float* Wk   = (const float*)d_in[4];
  const float* Wv   = (const float*)d_in[5];
  const float* Wo   = (const float*)d_in[6];
  const float* bo   = (const float*)d_in[7];
  const float* ln2g = (const float*)d_in[8];
  const float* ln2b = (const float*)d_in[9];
  const float* W1   = (const float*)d_in[10];
  const float* b1   = (const float*)d_in[11];
  const float* W2   = (const float*)d_in[12];
  const float* b2   = (const float*)d_in[13];
  unsigned short* ws = (unsigned short*)d_ws;

  const size_t need = (size_t)(1152 * 384 + 384 * 384 + 1536 * 384 + 384 * 1536) * 2;
  if (ws_size < need) return;

  hipLaunchKernelGGL(prep_w, dim3(1024), dim3(256), 0, stream, Wq, Wk, Wv, Wo, W1, W2, ws);

  const unsigned short* Wqkv = ws;
  const unsigned short* WoT  = ws + 1152 * 384;
  const unsigned short* W1T  = WoT + 384 * 384;
  const unsigned short* W2T  = W1T + 1536 * 384;
  int nblk = in_sizes[0] / (TT * CC);

  hipLaunchKernelGGL(attn_fwd, dim3(nblk), dim3(256), 0, stream,
                     x, ln1g, ln1b, bo, Wqkv, WoT, (float*)d_out);
  hipLaunchKernelGGL(mlp_fwd, dim3(nblk), dim3(256), 0, stream,
                     ln2g, ln2b, b1, b2, W1T, W2T, (float*)d_out);
}